// Round 10
// baseline (217.246 us; speedup 1.0000x reference)
//
#include <hip/hip_runtime.h>
#include <hip/hip_bf16.h>

// ---------------------------------------------------------------------------
// GAT 2-layer forward. N=50000, E=800000 (+N self loops).
// Round 23: revert fused kernel to R21 (1024-thr, best 196.3; R22's 512-thr
// convoy fix regressed) + channel-phase aggr2 for L2 locality. aggr2's h2b
// table is 6.4MB (> 4MB per-XCD L2 -> capacity misses on the random gather).
// Split aggr2 into 2 phases x 32 channels: per-phase slice = 3.2MB, fits
// per-XCD L2. Steer phase to XCD via the blockIdx%8 round-robin heuristic
// (phase=(bx&7)>>2; within=(bx>>3)*4+(bx&3)) so each XCD touches ONE slice.
// Wrong mapping = perf fallback only. L=4 lanes/edge (32ch), G=16 groups,
// D=2 preload (covers cnt<=32, ~95%). Score loads 2x (+3.4MB, trivial);
// ws recomputed per phase (VALU, cheap).
// R21: preload-then-consume gather pipeline. R20: fused aggr1+gemm2,
// 1 node/wave. R18: single-pass binned CSR build. R14: in-lane softmax
// weights, fused-score GEMMs. Assumes N <= 65536.
// ---------------------------------------------------------------------------

typedef __attribute__((ext_vector_type(8))) short bf16x8;
typedef __attribute__((ext_vector_type(4))) float f32x4;

#define BCHUNK 1024

__device__ __forceinline__ unsigned short f2bf(float f) {
  unsigned x = __float_as_uint(f);
  unsigned r = (x + 0x7fffu + ((x >> 16) & 1u)) >> 16;  // RNE
  return (unsigned short)r;
}
__device__ __forceinline__ float bf2f(unsigned short u) {
  return __uint_as_float(((unsigned)u) << 16);
}
__device__ __forceinline__ float bflo(unsigned u) {
  return __uint_as_float(u << 16);
}
__device__ __forceinline__ float bfhi(unsigned u) {
  return __uint_as_float(u & 0xffff0000u);
}

// inclusive 256-scan in LDS; returns inclusive sum at tid.
__device__ __forceinline__ int lds_scan256(int v, int* s) {
  int tid = threadIdx.x;
  s[tid] = v;
  __syncthreads();
  for (int o = 1; o < 256; o <<= 1) {
    int t = (tid >= o) ? s[tid - o] : 0;
    __syncthreads();
    s[tid] += t;
    __syncthreads();
  }
  return s[tid];
}

// ---- K1: single-pass binned scatter + weight conversion --------------------
__global__ __launch_bounds__(256) void b_scatter_cvt(
    const int* __restrict__ ei, int E, int N, int NBLK, int CAP,
    int* __restrict__ cur, unsigned* __restrict__ bkt2,
    const float* __restrict__ W1, const float* __restrict__ as1,
    const float* __restrict__ ad1, const float* __restrict__ W2,
    const float* __restrict__ as2, const float* __restrict__ ad2,
    unsigned short* __restrict__ W1t, unsigned short* __restrict__ W2t,
    unsigned short* __restrict__ wsb1, unsigned short* __restrict__ wsb2) {
  int tid = threadIdx.x;
  if ((int)blockIdx.x >= NBLK) {  // conversion blocks
    int i = ((int)blockIdx.x - NBLK) * 256 + tid;
    if (i < 16384) {                       // W1t
      int k = i >> 7, m = i & 127;
      W1t[m * 128 + k] = f2bf(W1[i]);
    } else if (i < 24576) {                // W2t
      int j = i - 16384;
      int k = j / 64, m = j % 64;
      W2t[m * 128 + k] = f2bf(W2[j]);
    } else if (i < 26624) {                // wsb1
      int j = i - 24576;
      int m = j >> 7, k = j & 127;
      float acc = 0.f;
      if (m < 4) {
        for (int c = 0; c < 32; ++c) acc += W1[k * 128 + m * 32 + c] * as1[m * 32 + c];
      } else if (m < 8) {
        for (int c = 0; c < 32; ++c) acc += W1[k * 128 + (m - 4) * 32 + c] * ad1[(m - 4) * 32 + c];
      }
      wsb1[j] = f2bf(acc);
    } else if (i < 28672) {                // wsb2
      int j = i - 26624;
      int m = j >> 7, k = j & 127;
      float acc = 0.f;
      if (m == 0) {
        for (int c = 0; c < 64; ++c) acc += W2[k * 64 + c] * as2[c];
      } else if (m == 1) {
        for (int c = 0; c < 64; ++c) acc += W2[k * 64 + c] * ad2[c];
      }
      wsb2[j] = f2bf(acc);
    }
    return;
  }
  __shared__ unsigned pk[BCHUNK];
  __shared__ unsigned char bk[BCHUNK];
  __shared__ int h[256];
  __shared__ int lcur[256];
  h[tid] = 0;
  __syncthreads();
  int ET = E + N;
  int base = blockIdx.x * BCHUNK;
  int lim = base + BCHUNK;
  if (lim > ET) lim = ET;
  int i = base + tid * 4;
  if (i + 3 < E && i + 4 <= lim) {
    int4 s4 = *(const int4*)(ei + i);
    int4 d4 = *(const int4*)(ei + E + i);
    int o = i - base;
    pk[o + 0] = (unsigned)s4.x | ((unsigned)(d4.x & 255) << 16);
    bk[o + 0] = (unsigned char)(d4.x >> 8); atomicAdd(&h[d4.x >> 8], 1);
    pk[o + 1] = (unsigned)s4.y | ((unsigned)(d4.y & 255) << 16);
    bk[o + 1] = (unsigned char)(d4.y >> 8); atomicAdd(&h[d4.y >> 8], 1);
    pk[o + 2] = (unsigned)s4.z | ((unsigned)(d4.z & 255) << 16);
    bk[o + 2] = (unsigned char)(d4.z >> 8); atomicAdd(&h[d4.z >> 8], 1);
    pk[o + 3] = (unsigned)s4.w | ((unsigned)(d4.w & 255) << 16);
    bk[o + 3] = (unsigned char)(d4.w >> 8); atomicAdd(&h[d4.w >> 8], 1);
  } else {
    for (int k = 0; k < 4; ++k) {
      int idx = i + k;
      if (idx < lim) {
        int s_, d;
        if (idx < E) { s_ = ei[idx]; d = ei[E + idx]; }
        else { s_ = idx - E; d = s_; }
        int o = idx - base;
        pk[o] = (unsigned)s_ | ((unsigned)(d & 255) << 16);
        bk[o] = (unsigned char)(d >> 8);
        atomicAdd(&h[d >> 8], 1);
      }
    }
  }
  __syncthreads();
  // claim per-bucket sub-range (device-scope atomic on global cursor)
  lcur[tid] = tid * CAP + atomicAdd(&cur[tid], h[tid]);
  __syncthreads();
  int cnt_ = lim - base;
  for (int o = tid; o < cnt_; o += 256) {
    int slot = atomicAdd(&lcur[bk[o]], 1);
    bkt2[slot] = pk[o];
  }
}

// ---- MFMA GEMM + fused scores (device body) --------------------------------
template <int AF32, int SC>
__device__ __forceinline__ void gemm_body(
    const void* __restrict__ Av, const unsigned short* __restrict__ Bt,
    const unsigned short* __restrict__ wsb, unsigned short* __restrict__ C,
    float* __restrict__ ssrc, float* __restrict__ sdst, int M, int row0) {
  const int K = 128;
  int lane = threadIdx.x & 63;
  int r = lane & 15, quad = lane >> 4;

  bf16x8 a[4];
  if (AF32) {
    const float* ap = (const float*)Av + (size_t)(row0 + r) * K + quad * 8;
#pragma unroll
    for (int t = 0; t < 4; ++t) {
      float4 lo = *(const float4*)(ap + t * 32);
      float4 hi = *(const float4*)(ap + t * 32 + 4);
      a[t][0] = (short)f2bf(lo.x); a[t][1] = (short)f2bf(lo.y);
      a[t][2] = (short)f2bf(lo.z); a[t][3] = (short)f2bf(lo.w);
      a[t][4] = (short)f2bf(hi.x); a[t][5] = (short)f2bf(hi.y);
      a[t][6] = (short)f2bf(hi.z); a[t][7] = (short)f2bf(hi.w);
    }
  } else {
    const unsigned short* ap = (const unsigned short*)Av + (size_t)(row0 + r) * K + quad * 8;
#pragma unroll
    for (int t = 0; t < 4; ++t) a[t] = *(const bf16x8*)(ap + t * 32);
  }

  for (int c0 = 0; c0 < M; c0 += 16) {
    f32x4 acc = {0.f, 0.f, 0.f, 0.f};
    const unsigned short* bp = Bt + (size_t)(c0 + r) * K + quad * 8;
#pragma unroll
    for (int t = 0; t < 4; ++t) {
      bf16x8 b = *(const bf16x8*)(bp + t * 32);
      acc = __builtin_amdgcn_mfma_f32_16x16x32_bf16(a[t], b, acc, 0, 0, 0);
    }
    unsigned short* cp = C + (size_t)(row0 + quad * 4) * M + c0 + r;
#pragma unroll
    for (int i = 0; i < 4; ++i) cp[(size_t)i * M] = f2bf(acc[i]);
  }

  // fused score tile: cols are wsb rows (0..SC-1 src, SC..2SC-1 dst)
  {
    f32x4 acc = {0.f, 0.f, 0.f, 0.f};
    const unsigned short* bp = wsb + r * 128 + quad * 8;
#pragma unroll
    for (int t = 0; t < 4; ++t) {
      bf16x8 b = *(const bf16x8*)(bp + t * 32);
      acc = __builtin_amdgcn_mfma_f32_16x16x32_bf16(a[t], b, acc, 0, 0, 0);
    }
    int row = row0 + quad * 4;
    if (r < SC) {
#pragma unroll
      for (int i = 0; i < 4; ++i) ssrc[(size_t)(row + i) * SC + r] = acc[i];
    } else if (r < 2 * SC) {
#pragma unroll
      for (int i = 0; i < 4; ++i) sdst[(size_t)(row + i) * SC + (r - SC)] = acc[i];
    }
  }
}

// ---- K2: bucket sort (from strided bkt2) || gemm1 --------------------------
__global__ __launch_bounds__(256) void k_sort_gemm1(
    const unsigned* __restrict__ bkt2, int CAP, const int* __restrict__ cur,
    unsigned* __restrict__ csr4, int* __restrict__ rowptr, int N, int ET,
    int NBKT,
    const float* __restrict__ x, const unsigned short* __restrict__ W1t,
    const unsigned short* __restrict__ wsb1, unsigned short* __restrict__ h1b,
    float* __restrict__ ssrc1, float* __restrict__ sdst1) {
  if ((int)blockIdx.x >= NBKT) {
    int row0 = ((int)blockIdx.x - NBKT) * 64 + (threadIdx.x >> 6) * 16;
    if (row0 >= N) return;
    gemm_body<1, 4>(x, W1t, wsb1, h1b, ssrc1, sdst1, 128, row0);
    return;
  }
  __shared__ int s[256];
  __shared__ int cnt[256];
  int b = blockIdx.x, tid = threadIdx.x;
  int tot = cur[tid];  // per-bucket totals (buckets >= NBKT stayed 0)
  (void)lds_scan256(tot, s);  // s[i] = inclusive sum -> csr4 bases
  int base = (b == 0) ? 0 : s[b - 1];
  int tb = s[b] - base;
  const unsigned* src = bkt2 + (size_t)b * CAP;
  __syncthreads();
  cnt[tid] = 0;
  __syncthreads();
  for (int k = tid; k < tb; k += 512) {
    unsigned p0 = src[k];
    int k1 = k + 256;
    unsigned p1 = (k1 < tb) ? src[k1] : 0u;
    atomicAdd(&cnt[p0 >> 16], 1);
    if (k1 < tb) atomicAdd(&cnt[p1 >> 16], 1);
  }
  __syncthreads();
  int v = cnt[tid];
  int incl = lds_scan256(v, s);
  int excl = incl - v;
  int node = (b << 8) + tid;
  if (node < N) rowptr[node] = base + excl;
  if (tid == 0 && b == NBKT - 1) rowptr[N] = ET;
  cnt[tid] = base + excl;  // becomes the scatter cursor
  __syncthreads();
  for (int k = tid; k < tb; k += 512) {
    unsigned p0 = src[k];
    int k1 = k + 256;
    unsigned p1 = (k1 < tb) ? src[k1] : 0u;
    int slot0 = atomicAdd(&cnt[p0 >> 16], 1);
    csr4[slot0] = p0;
    if (k1 < tb) {
      int slot1 = atomicAdd(&cnt[p1 >> 16], 1);
      csr4[slot1] = p1;
    }
  }
}

// ---- fused layer-1 aggregation + layer-2 GEMM (1024 threads, R21 form) -----
// Block = 16 waves = 16 nodes, ONE node per wave. D=6 preload pipeline:
// 6 shfl'd packets -> 12 back-to-back loads -> predicated consume. Tail for
// cnt > 24 uses the uniform-trip shfl loop. Then LDS stage + gemm2 tile.
__global__ __launch_bounds__(1024, 8) void gat_aggr1_gemm2(
    const int* __restrict__ rowptr, const unsigned* __restrict__ csr4,
    const float* __restrict__ ssrc, const float* __restrict__ sdst,
    const unsigned short* __restrict__ h, const float* __restrict__ bias,
    const unsigned short* __restrict__ W2t, const unsigned short* __restrict__ wsb2,
    unsigned short* __restrict__ h2b, float* __restrict__ ssrc2,
    float* __restrict__ sdst2, int N) {
  const int HC = 128, L = 16, G = 4, D = 6;  // D*G = 24 edges covered
  __shared__ unsigned short sm[16][136];  // +8 pad: 272B stride, 2-way banks
  int lane = threadIdx.x & 63;
  int wv = threadIdx.x >> 6;  // 0..15
  int base = blockIdx.x * 16;
  int l = lane & (L - 1);
  int g = lane / L;
  int c0 = l * 8;
  int hh = c0 >> 5;  // c0 / 32
  int n = base + wv;

  if (n < N) {
    int beg = rowptr[n];
    int cnt = rowptr[n + 1] - beg;
    float sdn = sdst[(size_t)n * 4 + hh];
    unsigned ce = 0;
    if (lane < cnt) ce = csr4[beg + lane];
    float a0 = 0.f, a1 = 0.f, a2 = 0.f, a3 = 0.f;
    float a4 = 0.f, a5 = 0.f, a6 = 0.f, a7 = 0.f, ws = 0.f;

    // ---- pipeline: preload D edges' scores + h rows ----
    int se[D]; float sc[D]; uint4 hv[D];
#pragma unroll
    for (int k = 0; k < D; ++k) {
      int j = g + k * G;                    // <= 23 < 64
      unsigned p = __shfl(ce, j, 64);       // uniform exec
      se[k] = (int)(p & 0xFFFF);            // invalid slots: ce=0 -> row 0 (hot)
    }
#pragma unroll
    for (int k = 0; k < D; ++k) sc[k] = ssrc[(size_t)se[k] * 4 + hh];
#pragma unroll
    for (int k = 0; k < D; ++k) hv[k] = *(const uint4*)(h + (size_t)se[k] * HC + c0);
#pragma unroll
    for (int k = 0; k < D; ++k) {
      int j = g + k * G;
      if (j < cnt) {
        float e = sc[k] + sdn;
        e = e > 0.f ? e : 0.2f * e;
        float w = __expf(e);
        uint4 u = hv[k];
        a0 = fmaf(w, bflo(u.x), a0); a1 = fmaf(w, bfhi(u.x), a1);
        a2 = fmaf(w, bflo(u.y), a2); a3 = fmaf(w, bfhi(u.y), a3);
        a4 = fmaf(w, bflo(u.z), a4); a5 = fmaf(w, bfhi(u.z), a5);
        a6 = fmaf(w, bflo(u.w), a6); a7 = fmaf(w, bfhi(u.w), a7);
        ws += w;
      }
    }
    // ---- tail: cnt > D*G (rare, ~4%) ----
    int T = (cnt + G - 1) / G;  // wave-uniform
    for (int k = D; k < T; ++k) {
      int j = g + k * G;
      unsigned p = __shfl(ce, j & 63, 64);  // uniform exec
      if (j < cnt) {
        if (j >= 64) p = csr4[beg + j];
        int s = (int)(p & 0xFFFF);
        float e = ssrc[(size_t)s * 4 + hh] + sdn;
        e = e > 0.f ? e : 0.2f * e;
        float w = __expf(e);
        uint4 u = *(const uint4*)(h + (size_t)s * HC + c0);
        a0 = fmaf(w, bflo(u.x), a0); a1 = fmaf(w, bfhi(u.x), a1);
        a2 = fmaf(w, bflo(u.y), a2); a3 = fmaf(w, bfhi(u.y), a3);
        a4 = fmaf(w, bflo(u.z), a4); a5 = fmaf(w, bfhi(u.z), a5);
        a6 = fmaf(w, bflo(u.w), a6); a7 = fmaf(w, bfhi(u.w), a7);
        ws += w;
      }
    }
#pragma unroll
    for (int off = L; off < 64; off <<= 1) {
      a0 += __shfl_xor(a0, off, 64); a1 += __shfl_xor(a1, off, 64);
      a2 += __shfl_xor(a2, off, 64); a3 += __shfl_xor(a3, off, 64);
      a4 += __shfl_xor(a4, off, 64); a5 += __shfl_xor(a5, off, 64);
      a6 += __shfl_xor(a6, off, 64); a7 += __shfl_xor(a7, off, 64);
      ws += __shfl_xor(ws, off, 64);
    }
    if (lane < L) {
      float inv = 1.f / ws;
      float4 bA = *(const float4*)(bias + c0);
      float4 bB = *(const float4*)(bias + c0 + 4);
      float v0 = fmaxf(fmaf(a0, inv, bA.x), 0.f);
      float v1 = fmaxf(fmaf(a1, inv, bA.y), 0.f);
      float v2 = fmaxf(fmaf(a2, inv, bA.z), 0.f);
      float v3 = fmaxf(fmaf(a3, inv, bA.w), 0.f);
      float v4 = fmaxf(fmaf(a4, inv, bB.x), 0.f);
      float v5 = fmaxf(fmaf(a5, inv, bB.y), 0.f);
      float v6 = fmaxf(fmaf(a6, inv, bB.z), 0.f);
      float v7 = fmaxf(fmaf(a7, inv, bB.w), 0.f);
      uint4 o;
      o.x = (unsigned)f2bf(v0) | ((unsigned)f2bf(v1) << 16);
      o.y = (unsigned)f2bf(v2) | ((unsigned)f2bf(v3) << 16);
      o.z = (unsigned)f2bf(v4) | ((unsigned)f2bf(v5) << 16);
      o.w = (unsigned)f2bf(v6) | ((unsigned)f2bf(v7) << 16);
      *(uint4*)&sm[wv][c0] = o;
    }
  } else if (lane < L) {
    *(uint4*)&sm[wv][c0] = make_uint4(0, 0, 0, 0);
  }
  __syncthreads();

  if (wv >= 5) return;
  // gemm2 from LDS: A = sm rows 0..15 (K=128)
  int r = lane & 15, quad = lane >> 4;
  bf16x8 a[4];
#pragma unroll
  for (int t = 0; t < 4; ++t) a[t] = *(const bf16x8*)&sm[r][quad * 8 + t * 32];
  if (wv < 4) {
    f32x4 acc = {0.f, 0.f, 0.f, 0.f};
    const unsigned short* bp = W2t + (size_t)(wv * 16 + r) * 128 + quad * 8;
#pragma unroll
    for (int t = 0; t < 4; ++t) {
      bf16x8 b = *(const bf16x8*)(bp + t * 32);
      acc = __builtin_amdgcn_mfma_f32_16x16x32_bf16(a[t], b, acc, 0, 0, 0);
    }
    unsigned short* cp = h2b + (size_t)(base + quad * 4) * 64 + wv * 16 + r;
#pragma unroll
    for (int i = 0; i < 4; ++i)
      if (base + quad * 4 + i < N) cp[(size_t)i * 64] = f2bf(acc[i]);
  } else {  // wv == 4: score tile
    f32x4 acc = {0.f, 0.f, 0.f, 0.f};
    const unsigned short* bp = wsb2 + r * 128 + quad * 8;
#pragma unroll
    for (int t = 0; t < 4; ++t) {
      bf16x8 b = *(const bf16x8*)(bp + t * 32);
      acc = __builtin_amdgcn_mfma_f32_16x16x32_bf16(a[t], b, acc, 0, 0, 0);
    }
    int row = base + quad * 4;
    if (r == 0) {
#pragma unroll
      for (int i = 0; i < 4; ++i) if (row + i < N) ssrc2[row + i] = acc[i];
    } else if (r == 1) {
#pragma unroll
      for (int i = 0; i < 4; ++i) if (row + i < N) sdst2[row + i] = acc[i];
    }
  }
}

// ---- layer-2 aggregator: 2 channel-phases x 32 ch, XCD-steered -------------
// phase = (blockIdx&7)>>2 (XCDs 0-3 -> phase 0, 4-7 -> phase 1 under the
// round-robin dispatch heuristic); within = (bx>>3)*4 + (bx&3) covers each
// (phase, node-group) exactly once. Per phase the h2b slice is 3.2MB ->
// fits per-XCD L2 -> capacity misses on the gather vanish. L=4 lanes/edge
// (32ch = 64B), G=16 edge groups, D=2 preload (covers cnt<=32).
__global__ __launch_bounds__(256, 8) void gat_aggr2(
    const int* __restrict__ rowptr, const unsigned* __restrict__ csr4,
    const float* __restrict__ ssrc, const float* __restrict__ sdst,
    const unsigned short* __restrict__ h, const float* __restrict__ bias,
    float* __restrict__ outv, int N) {
  const int HC = 64, L = 4, G = 16, D = 2;  // per-phase 32 channels
  int bx = blockIdx.x;
  int xcd = bx & 7;
  int phase = xcd >> 2;                    // 0 or 1
  int within = (bx >> 3) * 4 + (xcd & 3);  // node-group index
  int lane = threadIdx.x & 63;
  int n = within * 4 + (threadIdx.x >> 6);
  if (n >= N) return;
  int l = lane & (L - 1);   // 0..3
  int g = lane / L;         // 0..15
  int c0 = phase * 32 + l * 8;
  int beg = rowptr[n];
  int cnt = rowptr[n + 1] - beg;
  float sdn = sdst[n];

  unsigned ce = 0;
  if (lane < cnt) ce = csr4[beg + lane];

  float a0 = 0.f, a1 = 0.f, a2 = 0.f, a3 = 0.f;
  float a4 = 0.f, a5 = 0.f, a6 = 0.f, a7 = 0.f, ws = 0.f;

  // ---- pipeline: preload D edges ----
  int se[D]; float sc[D]; uint4 hv[D];
#pragma unroll
  for (int k = 0; k < D; ++k) {
    int j = g + k * G;                    // <= 31 < 64
    unsigned p = __shfl(ce, j, 64);
    se[k] = (int)(p & 0xFFFF);
  }
#pragma unroll
  for (int k = 0; k < D; ++k) sc[k] = ssrc[se[k]];
#pragma unroll
  for (int k = 0; k < D; ++k) hv[k] = *(const uint4*)(h + (size_t)se[k] * HC + c0);
#pragma unroll
  for (int k = 0; k < D; ++k) {
    int j = g + k * G;
    if (j < cnt) {
      float e = sc[k] + sdn;
      e = e > 0.f ? e : 0.2f * e;
      float w = __expf(e);
      uint4 u = hv[k];
      a0 = fmaf(w, bflo(u.x), a0); a1 = fmaf(w, bfhi(u.x), a1);
      a2 = fmaf(w, bflo(u.y), a2); a3 = fmaf(w, bfhi(u.y), a3);
      a4 = fmaf(w, bflo(u.z), a4); a5 = fmaf(w, bfhi(u.z), a5);
      a6 = fmaf(w, bflo(u.w), a6); a7 = fmaf(w, bfhi(u.w), a7);
      ws += w;
    }
  }
  // ---- tail: cnt > 32 (rare) ----
  int T = (cnt + G - 1) / G;  // wave-uniform
  for (int k = D; k < T; ++k) {
    int j = g + k * G;
    unsigned p = __shfl(ce, j & 63, 64);
    if (j < cnt) {
      if (j >= 64) p = csr4[beg + j];
      int s = (int)(p & 0xFFFF);
      float e = ssrc[s] + sdn;
      e = e > 0.f ? e : 0.2f * e;
      float w = __expf(e);
      uint4 u = *(const uint4*)(h + (size_t)s * HC + c0);
      a0 = fmaf(w, bflo(u.x), a0); a1 = fmaf(w, bfhi(u.x), a1);
      a2 = fmaf(w, bflo(u.y), a2); a3 = fmaf(w, bfhi(u.y), a3);
      a4 = fmaf(w, bflo(u.z), a4); a5 = fmaf(w, bfhi(u.z), a5);
      a6 = fmaf(w, bflo(u.w), a6); a7 = fmaf(w, bfhi(u.w), a7);
      ws += w;
    }
  }

#pragma unroll
  for (int off = L; off < 64; off <<= 1) {
    a0 += __shfl_xor(a0, off, 64); a1 += __shfl_xor(a1, off, 64);
    a2 += __shfl_xor(a2, off, 64); a3 += __shfl_xor(a3, off, 64);
    a4 += __shfl_xor(a4, off, 64); a5 += __shfl_xor(a5, off, 64);
    a6 += __shfl_xor(a6, off, 64); a7 += __shfl_xor(a7, off, 64);
    ws += __shfl_xor(ws, off, 64);
  }
  if (lane < L) {
    float inv = 1.f / ws;  // self-loop guarantees ws > 0
    float4 bA = *(const float4*)(bias + c0);
    float4 bB = *(const float4*)(bias + c0 + 4);
    float v0 = fmaf(a0, inv, bA.x), v1 = fmaf(a1, inv, bA.y);
    float v2 = fmaf(a2, inv, bA.z), v3 = fmaf(a3, inv, bA.w);
    float v4 = fmaf(a4, inv, bB.x), v5 = fmaf(a5, inv, bB.y);
    float v6 = fmaf(a6, inv, bB.z), v7 = fmaf(a7, inv, bB.w);
    float* op = outv + (size_t)n * HC + c0;
    *(float4*)op = make_float4(v0, v1, v2, v3);
    *(float4*)(op + 4) = make_float4(v4, v5, v6, v7);
  }
}

extern "C" void kernel_launch(void* const* d_in, const int* in_sizes, int n_in,
                              void* d_out, int out_size, void* d_ws, size_t ws_size,
                              hipStream_t stream) {
  const float* x   = (const float*)d_in[0];
  const int*   ei  = (const int*)d_in[1];
  const float* W1  = (const float*)d_in[2];
  const float* as1 = (const float*)d_in[3];
  const float* ad1 = (const float*)d_in[4];
  const float* b1  = (const float*)d_in[5];
  const float* W2  = (const float*)d_in[6];
  const float* as2 = (const float*)d_in[7];
  const float* ad2 = (const float*)d_in[8];
  const float* b2  = (const float*)d_in[9];

  const int N = in_sizes[0] / 128;  // 50000
  const int E = in_sizes[1] / 2;    // 800000
  const int ET = E + N;
  const int NBKT = (N + 255) >> 8;              // 196
  const int NBLK = (ET + BCHUNK - 1) / BCHUNK;  // 831
  const int CAP = 6144;                         // per-bucket capacity in bkt2

  char* pc = (char*)d_ws;
  auto alloc = [&](size_t bytes) -> void* {
    void* r = (void*)pc;
    pc += (bytes + 255) & ~(size_t)255;
    return r;
  };
  unsigned short* h1b   = (unsigned short*)alloc((size_t)N * 128 * 2);
  unsigned short* h2b   = (unsigned short*)alloc((size_t)N * 64 * 2);  // un-aliased
  unsigned short* W1t   = (unsigned short*)alloc(128 * 128 * 2);
  unsigned short* W2t   = (unsigned short*)alloc(64 * 128 * 2);
  unsigned short* wsb1  = (unsigned short*)alloc(16 * 128 * 2);
  unsigned short* wsb2  = (unsigned short*)alloc(16 * 128 * 2);
  float* ssrc1 = (float*)alloc((size_t)N * 4 * 4);
  float* sdst1 = (float*)alloc((size_t)N * 4 * 4);
  float* ssrc2 = (float*)alloc((size_t)N * 4);
  float* sdst2 = (float*)alloc((size_t)N * 4);
  int* rowptr = (int*)alloc((size_t)(N + 1) * 4);
  int* cur    = (int*)alloc(256 * 4);
  unsigned* bkt2 = (unsigned*)alloc((size_t)256 * CAP * 4);
  unsigned* csr4 = (unsigned*)alloc((size_t)ET * 4);

  dim3 blk(256);
  const int GB = (N + 63) / 64;  // 782 gemm blocks

  // zero the bucket cursors (workspace arrives poisoned each iteration)
  hipMemsetAsync(cur, 0, 256 * sizeof(int), stream);

  // ---- K1: binned scatter (count+scan+scatter merged) + weight conversion --
  b_scatter_cvt<<<dim3(NBLK + 112), blk, 0, stream>>>(
      ei, E, N, NBLK, CAP, cur, bkt2,
      W1, as1, ad1, W2, as2, ad2, W1t, W2t, wsb1, wsb2);

  // ---- K2: bucket sort || full gemm1 ---------------------------------------
  k_sort_gemm1<<<dim3(NBKT + GB), blk, 0, stream>>>(
      bkt2, CAP, cur, csr4, rowptr, N, ET, NBKT,
      x, W1t, wsb1, h1b, ssrc1, sdst1);

  // ---- fused: layer-1 aggregation + gemm2 (+scores2), 1024-thread blocks ---
  gat_aggr1_gemm2<<<dim3((N + 15) / 16), dim3(1024), 0, stream>>>(
      rowptr, csr4, ssrc1, sdst1, h1b, b1, W2t, wsb2, h2b, ssrc2, sdst2, N);

  // ---- layer 2 aggregation: 2 channel-phases, XCD-steered ------------------
  const int NB2 = (N + 3) / 4;                 // node-groups of 4
  const int GRID2 = ((NB2 + 3) / 4) * 8;       // 2 phases x NB2, %8 steering
  gat_aggr2<<<dim3(GRID2), blk, 0, stream>>>(
      rowptr, csr4, ssrc2, sdst2, h2b, b2, (float*)d_out, N);
}

// Round 11
// 198.731 us; speedup vs baseline: 1.0932x; 1.0932x over previous
//
#include <hip/hip_runtime.h>
#include <hip/hip_bf16.h>

// ---------------------------------------------------------------------------
// GAT 2-layer forward. N=50000, E=800000 (+N self loops).
// Round 24: REVERT to the R21 configuration (best verified: 196.3us).
// R22 (smaller convoy quantum) and R23 (channel-phased aggr2) both
// regressed; ledger across R20-R23: TLP +10%, MLP +5%, convoy -2%,
// L2-phasing -10% -- all knobs saturate the same ~2.1 TB/s random-gather
// limit (42% VALU, 26% HBM, 56% occ on the fused kernel). Structural
// arithmetic: ~333MB irreducible gather traffic at ~2.1 TB/s ~= 160us
// + serial CSR/GEMM chain ~= the observed 196us.
// Config: K1 single-pass binned scatter + weight cvt; K2 bucket-sort ||
// gemm1 (fused scores); fused aggr1+gemm2 (1024 thr, 1 node/wave, D=6
// preload pipeline); aggr2 (D=3 preload pipeline). In-lane softmax
// weights from L2-resident score tables. Assumes N <= 65536.
// ---------------------------------------------------------------------------

typedef __attribute__((ext_vector_type(8))) short bf16x8;
typedef __attribute__((ext_vector_type(4))) float f32x4;

#define BCHUNK 1024

__device__ __forceinline__ unsigned short f2bf(float f) {
  unsigned x = __float_as_uint(f);
  unsigned r = (x + 0x7fffu + ((x >> 16) & 1u)) >> 16;  // RNE
  return (unsigned short)r;
}
__device__ __forceinline__ float bf2f(unsigned short u) {
  return __uint_as_float(((unsigned)u) << 16);
}
__device__ __forceinline__ float bflo(unsigned u) {
  return __uint_as_float(u << 16);
}
__device__ __forceinline__ float bfhi(unsigned u) {
  return __uint_as_float(u & 0xffff0000u);
}

// inclusive 256-scan in LDS; returns inclusive sum at tid.
__device__ __forceinline__ int lds_scan256(int v, int* s) {
  int tid = threadIdx.x;
  s[tid] = v;
  __syncthreads();
  for (int o = 1; o < 256; o <<= 1) {
    int t = (tid >= o) ? s[tid - o] : 0;
    __syncthreads();
    s[tid] += t;
    __syncthreads();
  }
  return s[tid];
}

// ---- K1: single-pass binned scatter + weight conversion --------------------
__global__ __launch_bounds__(256) void b_scatter_cvt(
    const int* __restrict__ ei, int E, int N, int NBLK, int CAP,
    int* __restrict__ cur, unsigned* __restrict__ bkt2,
    const float* __restrict__ W1, const float* __restrict__ as1,
    const float* __restrict__ ad1, const float* __restrict__ W2,
    const float* __restrict__ as2, const float* __restrict__ ad2,
    unsigned short* __restrict__ W1t, unsigned short* __restrict__ W2t,
    unsigned short* __restrict__ wsb1, unsigned short* __restrict__ wsb2) {
  int tid = threadIdx.x;
  if ((int)blockIdx.x >= NBLK) {  // conversion blocks
    int i = ((int)blockIdx.x - NBLK) * 256 + tid;
    if (i < 16384) {                       // W1t
      int k = i >> 7, m = i & 127;
      W1t[m * 128 + k] = f2bf(W1[i]);
    } else if (i < 24576) {                // W2t
      int j = i - 16384;
      int k = j / 64, m = j % 64;
      W2t[m * 128 + k] = f2bf(W2[j]);
    } else if (i < 26624) {                // wsb1
      int j = i - 24576;
      int m = j >> 7, k = j & 127;
      float acc = 0.f;
      if (m < 4) {
        for (int c = 0; c < 32; ++c) acc += W1[k * 128 + m * 32 + c] * as1[m * 32 + c];
      } else if (m < 8) {
        for (int c = 0; c < 32; ++c) acc += W1[k * 128 + (m - 4) * 32 + c] * ad1[(m - 4) * 32 + c];
      }
      wsb1[j] = f2bf(acc);
    } else if (i < 28672) {                // wsb2
      int j = i - 26624;
      int m = j >> 7, k = j & 127;
      float acc = 0.f;
      if (m == 0) {
        for (int c = 0; c < 64; ++c) acc += W2[k * 64 + c] * as2[c];
      } else if (m == 1) {
        for (int c = 0; c < 64; ++c) acc += W2[k * 64 + c] * ad2[c];
      }
      wsb2[j] = f2bf(acc);
    }
    return;
  }
  __shared__ unsigned pk[BCHUNK];
  __shared__ unsigned char bk[BCHUNK];
  __shared__ int h[256];
  __shared__ int lcur[256];
  h[tid] = 0;
  __syncthreads();
  int ET = E + N;
  int base = blockIdx.x * BCHUNK;
  int lim = base + BCHUNK;
  if (lim > ET) lim = ET;
  int i = base + tid * 4;
  if (i + 3 < E && i + 4 <= lim) {
    int4 s4 = *(const int4*)(ei + i);
    int4 d4 = *(const int4*)(ei + E + i);
    int o = i - base;
    pk[o + 0] = (unsigned)s4.x | ((unsigned)(d4.x & 255) << 16);
    bk[o + 0] = (unsigned char)(d4.x >> 8); atomicAdd(&h[d4.x >> 8], 1);
    pk[o + 1] = (unsigned)s4.y | ((unsigned)(d4.y & 255) << 16);
    bk[o + 1] = (unsigned char)(d4.y >> 8); atomicAdd(&h[d4.y >> 8], 1);
    pk[o + 2] = (unsigned)s4.z | ((unsigned)(d4.z & 255) << 16);
    bk[o + 2] = (unsigned char)(d4.z >> 8); atomicAdd(&h[d4.z >> 8], 1);
    pk[o + 3] = (unsigned)s4.w | ((unsigned)(d4.w & 255) << 16);
    bk[o + 3] = (unsigned char)(d4.w >> 8); atomicAdd(&h[d4.w >> 8], 1);
  } else {
    for (int k = 0; k < 4; ++k) {
      int idx = i + k;
      if (idx < lim) {
        int s_, d;
        if (idx < E) { s_ = ei[idx]; d = ei[E + idx]; }
        else { s_ = idx - E; d = s_; }
        int o = idx - base;
        pk[o] = (unsigned)s_ | ((unsigned)(d & 255) << 16);
        bk[o] = (unsigned char)(d >> 8);
        atomicAdd(&h[d >> 8], 1);
      }
    }
  }
  __syncthreads();
  // claim per-bucket sub-range (device-scope atomic on global cursor)
  lcur[tid] = tid * CAP + atomicAdd(&cur[tid], h[tid]);
  __syncthreads();
  int cnt_ = lim - base;
  for (int o = tid; o < cnt_; o += 256) {
    int slot = atomicAdd(&lcur[bk[o]], 1);
    bkt2[slot] = pk[o];
  }
}

// ---- MFMA GEMM + fused scores (device body) --------------------------------
template <int AF32, int SC>
__device__ __forceinline__ void gemm_body(
    const void* __restrict__ Av, const unsigned short* __restrict__ Bt,
    const unsigned short* __restrict__ wsb, unsigned short* __restrict__ C,
    float* __restrict__ ssrc, float* __restrict__ sdst, int M, int row0) {
  const int K = 128;
  int lane = threadIdx.x & 63;
  int r = lane & 15, quad = lane >> 4;

  bf16x8 a[4];
  if (AF32) {
    const float* ap = (const float*)Av + (size_t)(row0 + r) * K + quad * 8;
#pragma unroll
    for (int t = 0; t < 4; ++t) {
      float4 lo = *(const float4*)(ap + t * 32);
      float4 hi = *(const float4*)(ap + t * 32 + 4);
      a[t][0] = (short)f2bf(lo.x); a[t][1] = (short)f2bf(lo.y);
      a[t][2] = (short)f2bf(lo.z); a[t][3] = (short)f2bf(lo.w);
      a[t][4] = (short)f2bf(hi.x); a[t][5] = (short)f2bf(hi.y);
      a[t][6] = (short)f2bf(hi.z); a[t][7] = (short)f2bf(hi.w);
    }
  } else {
    const unsigned short* ap = (const unsigned short*)Av + (size_t)(row0 + r) * K + quad * 8;
#pragma unroll
    for (int t = 0; t < 4; ++t) a[t] = *(const bf16x8*)(ap + t * 32);
  }

  for (int c0 = 0; c0 < M; c0 += 16) {
    f32x4 acc = {0.f, 0.f, 0.f, 0.f};
    const unsigned short* bp = Bt + (size_t)(c0 + r) * K + quad * 8;
#pragma unroll
    for (int t = 0; t < 4; ++t) {
      bf16x8 b = *(const bf16x8*)(bp + t * 32);
      acc = __builtin_amdgcn_mfma_f32_16x16x32_bf16(a[t], b, acc, 0, 0, 0);
    }
    unsigned short* cp = C + (size_t)(row0 + quad * 4) * M + c0 + r;
#pragma unroll
    for (int i = 0; i < 4; ++i) cp[(size_t)i * M] = f2bf(acc[i]);
  }

  // fused score tile: cols are wsb rows (0..SC-1 src, SC..2SC-1 dst)
  {
    f32x4 acc = {0.f, 0.f, 0.f, 0.f};
    const unsigned short* bp = wsb + r * 128 + quad * 8;
#pragma unroll
    for (int t = 0; t < 4; ++t) {
      bf16x8 b = *(const bf16x8*)(bp + t * 32);
      acc = __builtin_amdgcn_mfma_f32_16x16x32_bf16(a[t], b, acc, 0, 0, 0);
    }
    int row = row0 + quad * 4;
    if (r < SC) {
#pragma unroll
      for (int i = 0; i < 4; ++i) ssrc[(size_t)(row + i) * SC + r] = acc[i];
    } else if (r < 2 * SC) {
#pragma unroll
      for (int i = 0; i < 4; ++i) sdst[(size_t)(row + i) * SC + (r - SC)] = acc[i];
    }
  }
}

// ---- K2: bucket sort (from strided bkt2) || gemm1 --------------------------
__global__ __launch_bounds__(256) void k_sort_gemm1(
    const unsigned* __restrict__ bkt2, int CAP, const int* __restrict__ cur,
    unsigned* __restrict__ csr4, int* __restrict__ rowptr, int N, int ET,
    int NBKT,
    const float* __restrict__ x, const unsigned short* __restrict__ W1t,
    const unsigned short* __restrict__ wsb1, unsigned short* __restrict__ h1b,
    float* __restrict__ ssrc1, float* __restrict__ sdst1) {
  if ((int)blockIdx.x >= NBKT) {
    int row0 = ((int)blockIdx.x - NBKT) * 64 + (threadIdx.x >> 6) * 16;
    if (row0 >= N) return;
    gemm_body<1, 4>(x, W1t, wsb1, h1b, ssrc1, sdst1, 128, row0);
    return;
  }
  __shared__ int s[256];
  __shared__ int cnt[256];
  int b = blockIdx.x, tid = threadIdx.x;
  int tot = cur[tid];  // per-bucket totals (buckets >= NBKT stayed 0)
  (void)lds_scan256(tot, s);  // s[i] = inclusive sum -> csr4 bases
  int base = (b == 0) ? 0 : s[b - 1];
  int tb = s[b] - base;
  const unsigned* src = bkt2 + (size_t)b * CAP;
  __syncthreads();
  cnt[tid] = 0;
  __syncthreads();
  for (int k = tid; k < tb; k += 512) {
    unsigned p0 = src[k];
    int k1 = k + 256;
    unsigned p1 = (k1 < tb) ? src[k1] : 0u;
    atomicAdd(&cnt[p0 >> 16], 1);
    if (k1 < tb) atomicAdd(&cnt[p1 >> 16], 1);
  }
  __syncthreads();
  int v = cnt[tid];
  int incl = lds_scan256(v, s);
  int excl = incl - v;
  int node = (b << 8) + tid;
  if (node < N) rowptr[node] = base + excl;
  if (tid == 0 && b == NBKT - 1) rowptr[N] = ET;
  cnt[tid] = base + excl;  // becomes the scatter cursor
  __syncthreads();
  for (int k = tid; k < tb; k += 512) {
    unsigned p0 = src[k];
    int k1 = k + 256;
    unsigned p1 = (k1 < tb) ? src[k1] : 0u;
    int slot0 = atomicAdd(&cnt[p0 >> 16], 1);
    csr4[slot0] = p0;
    if (k1 < tb) {
      int slot1 = atomicAdd(&cnt[p1 >> 16], 1);
      csr4[slot1] = p1;
    }
  }
}

// ---- fused layer-1 aggregation + layer-2 GEMM (1024 threads) ---------------
// Block = 16 waves = 16 nodes, ONE node per wave. Aggregation is a D=6
// preload-then-consume pipeline: 6 shfl'd packets -> 12 back-to-back loads
// -> predicated consume (order identical to the sequential loop). Tail for
// cnt > 24 uses the uniform-trip shfl loop. Then LDS stage + gemm2 tile.
__global__ __launch_bounds__(1024, 8) void gat_aggr1_gemm2(
    const int* __restrict__ rowptr, const unsigned* __restrict__ csr4,
    const float* __restrict__ ssrc, const float* __restrict__ sdst,
    const unsigned short* __restrict__ h, const float* __restrict__ bias,
    const unsigned short* __restrict__ W2t, const unsigned short* __restrict__ wsb2,
    unsigned short* __restrict__ h2b, float* __restrict__ ssrc2,
    float* __restrict__ sdst2, int N) {
  const int HC = 128, L = 16, G = 4, D = 6;  // D*G = 24 edges covered
  __shared__ unsigned short sm[16][136];  // +8 pad: 272B stride, 2-way banks
  int lane = threadIdx.x & 63;
  int wv = threadIdx.x >> 6;  // 0..15
  int base = blockIdx.x * 16;
  int l = lane & (L - 1);
  int g = lane / L;
  int c0 = l * 8;
  int hh = c0 >> 5;  // c0 / 32
  int n = base + wv;

  if (n < N) {
    int beg = rowptr[n];
    int cnt = rowptr[n + 1] - beg;
    float sdn = sdst[(size_t)n * 4 + hh];
    unsigned ce = 0;
    if (lane < cnt) ce = csr4[beg + lane];
    float a0 = 0.f, a1 = 0.f, a2 = 0.f, a3 = 0.f;
    float a4 = 0.f, a5 = 0.f, a6 = 0.f, a7 = 0.f, ws = 0.f;

    // ---- pipeline: preload D edges' scores + h rows ----
    int se[D]; float sc[D]; uint4 hv[D];
#pragma unroll
    for (int k = 0; k < D; ++k) {
      int j = g + k * G;                    // <= 23 < 64
      unsigned p = __shfl(ce, j, 64);       // uniform exec
      se[k] = (int)(p & 0xFFFF);            // invalid slots: ce=0 -> row 0 (hot)
    }
#pragma unroll
    for (int k = 0; k < D; ++k) sc[k] = ssrc[(size_t)se[k] * 4 + hh];
#pragma unroll
    for (int k = 0; k < D; ++k) hv[k] = *(const uint4*)(h + (size_t)se[k] * HC + c0);
#pragma unroll
    for (int k = 0; k < D; ++k) {
      int j = g + k * G;
      if (j < cnt) {
        float e = sc[k] + sdn;
        e = e > 0.f ? e : 0.2f * e;
        float w = __expf(e);
        uint4 u = hv[k];
        a0 = fmaf(w, bflo(u.x), a0); a1 = fmaf(w, bfhi(u.x), a1);
        a2 = fmaf(w, bflo(u.y), a2); a3 = fmaf(w, bfhi(u.y), a3);
        a4 = fmaf(w, bflo(u.z), a4); a5 = fmaf(w, bfhi(u.z), a5);
        a6 = fmaf(w, bflo(u.w), a6); a7 = fmaf(w, bfhi(u.w), a7);
        ws += w;
      }
    }
    // ---- tail: cnt > D*G (rare, ~4%) ----
    int T = (cnt + G - 1) / G;  // wave-uniform
    for (int k = D; k < T; ++k) {
      int j = g + k * G;
      unsigned p = __shfl(ce, j & 63, 64);  // uniform exec
      if (j < cnt) {
        if (j >= 64) p = csr4[beg + j];
        int s = (int)(p & 0xFFFF);
        float e = ssrc[(size_t)s * 4 + hh] + sdn;
        e = e > 0.f ? e : 0.2f * e;
        float w = __expf(e);
        uint4 u = *(const uint4*)(h + (size_t)s * HC + c0);
        a0 = fmaf(w, bflo(u.x), a0); a1 = fmaf(w, bfhi(u.x), a1);
        a2 = fmaf(w, bflo(u.y), a2); a3 = fmaf(w, bfhi(u.y), a3);
        a4 = fmaf(w, bflo(u.z), a4); a5 = fmaf(w, bfhi(u.z), a5);
        a6 = fmaf(w, bflo(u.w), a6); a7 = fmaf(w, bfhi(u.w), a7);
        ws += w;
      }
    }
#pragma unroll
    for (int off = L; off < 64; off <<= 1) {
      a0 += __shfl_xor(a0, off, 64); a1 += __shfl_xor(a1, off, 64);
      a2 += __shfl_xor(a2, off, 64); a3 += __shfl_xor(a3, off, 64);
      a4 += __shfl_xor(a4, off, 64); a5 += __shfl_xor(a5, off, 64);
      a6 += __shfl_xor(a6, off, 64); a7 += __shfl_xor(a7, off, 64);
      ws += __shfl_xor(ws, off, 64);
    }
    if (lane < L) {
      float inv = 1.f / ws;
      float4 bA = *(const float4*)(bias + c0);
      float4 bB = *(const float4*)(bias + c0 + 4);
      float v0 = fmaxf(fmaf(a0, inv, bA.x), 0.f);
      float v1 = fmaxf(fmaf(a1, inv, bA.y), 0.f);
      float v2 = fmaxf(fmaf(a2, inv, bA.z), 0.f);
      float v3 = fmaxf(fmaf(a3, inv, bA.w), 0.f);
      float v4 = fmaxf(fmaf(a4, inv, bB.x), 0.f);
      float v5 = fmaxf(fmaf(a5, inv, bB.y), 0.f);
      float v6 = fmaxf(fmaf(a6, inv, bB.z), 0.f);
      float v7 = fmaxf(fmaf(a7, inv, bB.w), 0.f);
      uint4 o;
      o.x = (unsigned)f2bf(v0) | ((unsigned)f2bf(v1) << 16);
      o.y = (unsigned)f2bf(v2) | ((unsigned)f2bf(v3) << 16);
      o.z = (unsigned)f2bf(v4) | ((unsigned)f2bf(v5) << 16);
      o.w = (unsigned)f2bf(v6) | ((unsigned)f2bf(v7) << 16);
      *(uint4*)&sm[wv][c0] = o;
    }
  } else if (lane < L) {
    *(uint4*)&sm[wv][c0] = make_uint4(0, 0, 0, 0);
  }
  __syncthreads();

  if (wv >= 5) return;
  // gemm2 from LDS: A = sm rows 0..15 (K=128)
  int r = lane & 15, quad = lane >> 4;
  bf16x8 a[4];
#pragma unroll
  for (int t = 0; t < 4; ++t) a[t] = *(const bf16x8*)&sm[r][quad * 8 + t * 32];
  if (wv < 4) {
    f32x4 acc = {0.f, 0.f, 0.f, 0.f};
    const unsigned short* bp = W2t + (size_t)(wv * 16 + r) * 128 + quad * 8;
#pragma unroll
    for (int t = 0; t < 4; ++t) {
      bf16x8 b = *(const bf16x8*)(bp + t * 32);
      acc = __builtin_amdgcn_mfma_f32_16x16x32_bf16(a[t], b, acc, 0, 0, 0);
    }
    unsigned short* cp = h2b + (size_t)(base + quad * 4) * 64 + wv * 16 + r;
#pragma unroll
    for (int i = 0; i < 4; ++i)
      if (base + quad * 4 + i < N) cp[(size_t)i * 64] = f2bf(acc[i]);
  } else {  // wv == 4: score tile
    f32x4 acc = {0.f, 0.f, 0.f, 0.f};
    const unsigned short* bp = wsb2 + r * 128 + quad * 8;
#pragma unroll
    for (int t = 0; t < 4; ++t) {
      bf16x8 b = *(const bf16x8*)(bp + t * 32);
      acc = __builtin_amdgcn_mfma_f32_16x16x32_bf16(a[t], b, acc, 0, 0, 0);
    }
    int row = base + quad * 4;
    if (r == 0) {
#pragma unroll
      for (int i = 0; i < 4; ++i) if (row + i < N) ssrc2[row + i] = acc[i];
    } else if (r == 1) {
#pragma unroll
      for (int i = 0; i < 4; ++i) if (row + i < N) sdst2[row + i] = acc[i];
    }
  }
}

// ---- layer-2 aggregator: D=3 preload pipeline (L=8, G=8, 128B/edge) --------
__global__ __launch_bounds__(256) void gat_aggr2(
    const int* __restrict__ rowptr, const unsigned* __restrict__ csr4,
    const float* __restrict__ ssrc, const float* __restrict__ sdst,
    const unsigned short* __restrict__ h, const float* __restrict__ bias,
    float* __restrict__ outv, int N) {
  const int HC = 64, L = 8, G = 8, D = 3;  // D*G = 24 edges covered
  int lane = threadIdx.x & 63;
  int n = blockIdx.x * 4 + (threadIdx.x >> 6);
  if (n >= N) return;
  int l = lane & (L - 1);
  int g = lane / L;  // 0..7
  int c0 = l * 8;
  int beg = rowptr[n];
  int cnt = rowptr[n + 1] - beg;
  float sdn = sdst[n];

  unsigned ce = 0;
  if (lane < cnt) ce = csr4[beg + lane];

  float a0 = 0.f, a1 = 0.f, a2 = 0.f, a3 = 0.f;
  float a4 = 0.f, a5 = 0.f, a6 = 0.f, a7 = 0.f, ws = 0.f;

  // ---- pipeline: preload D edges ----
  int se[D]; float sc[D]; uint4 hv[D];
#pragma unroll
  for (int k = 0; k < D; ++k) {
    int j = g + k * G;                    // <= 23 < 64
    unsigned p = __shfl(ce, j, 64);
    se[k] = (int)(p & 0xFFFF);
  }
#pragma unroll
  for (int k = 0; k < D; ++k) sc[k] = ssrc[se[k]];
#pragma unroll
  for (int k = 0; k < D; ++k) hv[k] = *(const uint4*)(h + (size_t)se[k] * HC + c0);
#pragma unroll
  for (int k = 0; k < D; ++k) {
    int j = g + k * G;
    if (j < cnt) {
      float e = sc[k] + sdn;
      e = e > 0.f ? e : 0.2f * e;
      float w = __expf(e);
      uint4 u = hv[k];
      a0 = fmaf(w, bflo(u.x), a0); a1 = fmaf(w, bfhi(u.x), a1);
      a2 = fmaf(w, bflo(u.y), a2); a3 = fmaf(w, bfhi(u.y), a3);
      a4 = fmaf(w, bflo(u.z), a4); a5 = fmaf(w, bfhi(u.z), a5);
      a6 = fmaf(w, bflo(u.w), a6); a7 = fmaf(w, bfhi(u.w), a7);
      ws += w;
    }
  }
  // ---- tail: cnt > 24 (rare) ----
  int T = (cnt + G - 1) / G;  // wave-uniform
  for (int k = D; k < T; ++k) {
    int j = g + k * G;
    unsigned p = __shfl(ce, j & 63, 64);
    if (j < cnt) {
      if (j >= 64) p = csr4[beg + j];
      int s = (int)(p & 0xFFFF);
      float e = ssrc[s] + sdn;
      e = e > 0.f ? e : 0.2f * e;
      float w = __expf(e);
      uint4 u = *(const uint4*)(h + (size_t)s * HC + c0);
      a0 = fmaf(w, bflo(u.x), a0); a1 = fmaf(w, bfhi(u.x), a1);
      a2 = fmaf(w, bflo(u.y), a2); a3 = fmaf(w, bfhi(u.y), a3);
      a4 = fmaf(w, bflo(u.z), a4); a5 = fmaf(w, bfhi(u.z), a5);
      a6 = fmaf(w, bflo(u.w), a6); a7 = fmaf(w, bfhi(u.w), a7);
      ws += w;
    }
  }

#pragma unroll
  for (int off = L; off < 64; off <<= 1) {
    a0 += __shfl_xor(a0, off, 64); a1 += __shfl_xor(a1, off, 64);
    a2 += __shfl_xor(a2, off, 64); a3 += __shfl_xor(a3, off, 64);
    a4 += __shfl_xor(a4, off, 64); a5 += __shfl_xor(a5, off, 64);
    a6 += __shfl_xor(a6, off, 64); a7 += __shfl_xor(a7, off, 64);
    ws += __shfl_xor(ws, off, 64);
  }
  if (lane < L) {
    float inv = 1.f / ws;  // self-loop guarantees ws > 0
    float4 bA = *(const float4*)(bias + c0);
    float4 bB = *(const float4*)(bias + c0 + 4);
    float v0 = fmaf(a0, inv, bA.x), v1 = fmaf(a1, inv, bA.y);
    float v2 = fmaf(a2, inv, bA.z), v3 = fmaf(a3, inv, bA.w);
    float v4 = fmaf(a4, inv, bB.x), v5 = fmaf(a5, inv, bB.y);
    float v6 = fmaf(a6, inv, bB.z), v7 = fmaf(a7, inv, bB.w);
    float* op = outv + (size_t)n * HC + c0;
    *(float4*)op = make_float4(v0, v1, v2, v3);
    *(float4*)(op + 4) = make_float4(v4, v5, v6, v7);
  }
}

extern "C" void kernel_launch(void* const* d_in, const int* in_sizes, int n_in,
                              void* d_out, int out_size, void* d_ws, size_t ws_size,
                              hipStream_t stream) {
  const float* x   = (const float*)d_in[0];
  const int*   ei  = (const int*)d_in[1];
  const float* W1  = (const float*)d_in[2];
  const float* as1 = (const float*)d_in[3];
  const float* ad1 = (const float*)d_in[4];
  const float* b1  = (const float*)d_in[5];
  const float* W2  = (const float*)d_in[6];
  const float* as2 = (const float*)d_in[7];
  const float* ad2 = (const float*)d_in[8];
  const float* b2  = (const float*)d_in[9];

  const int N = in_sizes[0] / 128;  // 50000
  const int E = in_sizes[1] / 2;    // 800000
  const int ET = E + N;
  const int NBKT = (N + 255) >> 8;              // 196
  const int NBLK = (ET + BCHUNK - 1) / BCHUNK;  // 831
  const int CAP = 6144;                         // per-bucket capacity in bkt2

  char* pc = (char*)d_ws;
  auto alloc = [&](size_t bytes) -> void* {
    void* r = (void*)pc;
    pc += (bytes + 255) & ~(size_t)255;
    return r;
  };
  unsigned short* h1b   = (unsigned short*)alloc((size_t)N * 128 * 2);
  unsigned short* h2b   = (unsigned short*)alloc((size_t)N * 64 * 2);  // un-aliased
  unsigned short* W1t   = (unsigned short*)alloc(128 * 128 * 2);
  unsigned short* W2t   = (unsigned short*)alloc(64 * 128 * 2);
  unsigned short* wsb1  = (unsigned short*)alloc(16 * 128 * 2);
  unsigned short* wsb2  = (unsigned short*)alloc(16 * 128 * 2);
  float* ssrc1 = (float*)alloc((size_t)N * 4 * 4);
  float* sdst1 = (float*)alloc((size_t)N * 4 * 4);
  float* ssrc2 = (float*)alloc((size_t)N * 4);
  float* sdst2 = (float*)alloc((size_t)N * 4);
  int* rowptr = (int*)alloc((size_t)(N + 1) * 4);
  int* cur    = (int*)alloc(256 * 4);
  unsigned* bkt2 = (unsigned*)alloc((size_t)256 * CAP * 4);
  unsigned* csr4 = (unsigned*)alloc((size_t)ET * 4);

  dim3 blk(256);
  const int GB = (N + 63) / 64;  // 782 gemm blocks

  // zero the bucket cursors (workspace arrives poisoned each iteration)
  hipMemsetAsync(cur, 0, 256 * sizeof(int), stream);

  // ---- K1: binned scatter (count+scan+scatter merged) + weight conversion --
  b_scatter_cvt<<<dim3(NBLK + 112), blk, 0, stream>>>(
      ei, E, N, NBLK, CAP, cur, bkt2,
      W1, as1, ad1, W2, as2, ad2, W1t, W2t, wsb1, wsb2);

  // ---- K2: bucket sort || full gemm1 ---------------------------------------
  k_sort_gemm1<<<dim3(NBKT + GB), blk, 0, stream>>>(
      bkt2, CAP, cur, csr4, rowptr, N, ET, NBKT,
      x, W1t, wsb1, h1b, ssrc1, sdst1);

  // ---- fused: layer-1 aggregation + gemm2 (+scores2), 1024-thread blocks ---
  gat_aggr1_gemm2<<<dim3((N + 15) / 16), dim3(1024), 0, stream>>>(
      rowptr, csr4, ssrc1, sdst1, h1b, b1, W2t, wsb2, h2b, ssrc2, sdst2, N);

  // ---- layer 2 aggregation: 1 head x 64, +bias (f32 out) -------------------
  gat_aggr2<<<dim3((N + 3) / 4), blk, 0, stream>>>(
      rowptr, csr4, ssrc2, sdst2, h2b, b2, (float*)d_out, N);
}